// Round 5
// baseline (434.075 us; speedup 1.0000x reference)
//
#include <hip/hip_runtime.h>

// OHEM loss, MI355X. B=8, C=19, H=512, W=1024.
// v6: long-run staging. Accounting across rounds shows harness fixed cost
// F~248us and ohem_main ~160us (=2.1 TB/s effective, 1/3 of sequential rate),
// INVARIANT across occupancy/depth/destination changes. Hypothesis: the
// 19-stream x 1KB-burst x 2MB(2^21)-stride pattern is the limiter (DRAM row
// thrash / pow2 hashing). Single-variable fix: wave w stages classes
// {c: c%4==w} for the WHOLE 4KB tile as 4 back-to-back global_load_lds
// -> 4KB contiguous runs per class (4x longer), same bytes, same LDS layout.
// Waves now consume each other's data -> counted vmcnt THEN raw s_barrier
// (NOT __syncthreads: it emits vmcnt(0) and would drain the pipeline).
// Main path: n_over = count(loss>0.7) >> MIN_KEPT, so kept_sum ==
// sum(loss where loss>0.7); no sort. Fallback via bisection in finalize.

#define BB 8
#define CC 19
#define HW (512 * 1024)
#define THRESH 0.7f
#define MIN_KEPT 10000
#define QHW (HW / 4)           // 131072 quads per batch
#define TILE 256               // quads per tile (one per thread)
#define SEGS (QHW / TILE)      // 512 tiles per batch
#define NTILE (SEGS * BB)      // 4096 tiles total
#define NPBLK 256              // persistent blocks (1 per CU)
#define TPB (NTILE / NPBLK)    // 16 tiles per block (16 | 512 -> same batch)

#define BUFF 19456             // floats per LDS buffer (19 * 4 KB = 77824 B)

// async 16 B/lane global->LDS DMA (dest = wave-uniform base + lane*16)
#define GLOAD_LDS16(g, l)                                                     \
    __builtin_amdgcn_global_load_lds(                                         \
        (const __attribute__((address_space(1))) void*)(g),                   \
        (__attribute__((address_space(3))) void*)(l), 16, 0, 0)

__device__ __forceinline__ float wave_reduce_f(float v) {
#pragma unroll
    for (int off = 32; off > 0; off >>= 1) v += __shfl_down(v, off, 64);
    return v;
}
__device__ __forceinline__ int wave_reduce_i(int v) {
#pragma unroll
    for (int off = 32; off > 0; off >>= 1) v += __shfl_down(v, off, 64);
    return v;
}

// wave wid stages classes {c : c%4==wid} of one tile: per class a 4-KB
// CONTIGUOUS run issued as 4 back-to-back 16B/lane DMA instructions.
// DMA count: wid 0..2 -> 20, wid 3 -> 16.
__device__ __forceinline__ void stage_wave(const float* pb, int seg,
                                           float* lbuf, int wid, int lane) {
    const float* gp = pb + (size_t)seg * (TILE * 4);
#pragma unroll
    for (int c = wid; c < CC; c += 4) {
        const float* g = gp + (size_t)c * HW;
        float* l = lbuf + c * (TILE * 4);
#pragma unroll
        for (int j = 0; j < 4; ++j)
            GLOAD_LDS16(g + j * 256 + lane * 4, l + j * 256 + lane * 4);
    }
}

// counted wait for own previous-tile group (DMAs + 1 target load), then
// raw barrier => ALL waves' current-tile data resident in LDS.
__device__ __forceinline__ void wait_and_barrier(int wid) {
    __builtin_amdgcn_sched_barrier(0);
    if (wid == 3) asm volatile("s_waitcnt vmcnt(17)" ::: "memory");
    else          asm volatile("s_waitcnt vmcnt(21)" ::: "memory");
    __builtin_amdgcn_s_barrier();
    __builtin_amdgcn_sched_barrier(0);
}
__device__ __forceinline__ void read_done_barrier() {
    __builtin_amdgcn_sched_barrier(0);
    __builtin_amdgcn_s_barrier();
    __builtin_amdgcn_sched_barrier(0);
}

// compute one tile from an LDS buffer; accumulate kept sum/count
__device__ __forceinline__ void tile_compute(const float* base, int4 t, int tid,
                                             float& sloc, int& cloc) {
    const float4* lv = (const float4*)base;
    // pass 1: componentwise max over classes
    float4 m = lv[tid];
#pragma unroll
    for (int c = 1; c < CC; ++c) {
        const float4 a = lv[c * TILE + tid];
        m.x = fmaxf(m.x, a.x);
        m.y = fmaxf(m.y, a.y);
        m.z = fmaxf(m.z, a.z);
        m.w = fmaxf(m.w, a.w);
    }
    // pass 2: sum exp(a - m) + select logit[target]
    float4 s = {0.f, 0.f, 0.f, 0.f};
    float4 tv = {0.f, 0.f, 0.f, 0.f};
#pragma unroll
    for (int c = 0; c < CC; ++c) {
        const float4 a = lv[c * TILE + tid];
        s.x += __expf(a.x - m.x);
        s.y += __expf(a.y - m.y);
        s.z += __expf(a.z - m.z);
        s.w += __expf(a.w - m.w);
        tv.x = (t.x == c) ? a.x : tv.x;
        tv.y = (t.y == c) ? a.y : tv.y;
        tv.z = (t.z == c) ? a.z : tv.z;
        tv.w = (t.w == c) ? a.w : tv.w;
    }
    const float l0 = m.x - tv.x + __logf(s.x);
    const float l1 = m.y - tv.y + __logf(s.y);
    const float l2 = m.z - tv.z + __logf(s.z);
    const float l3 = m.w - tv.w + __logf(s.w);
    if (l0 > THRESH) { sloc += l0; ++cloc; }
    if (l1 > THRESH) { sloc += l1; ++cloc; }
    if (l2 > THRESH) { sloc += l2; ++cloc; }
    if (l3 > THRESH) { sloc += l3; ++cloc; }
}

// ---------------- main: persistent pipelined loss pass ----------------
__global__ __launch_bounds__(256) void ohem_main(
    const float* __restrict__ preds, const int* __restrict__ tgts,
    float* __restrict__ sums, int* __restrict__ counts) {

    __shared__ float cls[2 * BUFF];   // 155648 B
    __shared__ float sbuf[4];
    __shared__ int cbuf[4];

    const int tid = threadIdx.x;
    const int wid = tid >> 6;
    const int lane = tid & 63;
    const int g0 = blockIdx.x * TPB;       // first tile of this block
    const int b = g0 / SEGS;               // batch (constant per block)
    const int seg0 = g0 % SEGS;

    const float* pb = preds + (size_t)b * CC * HW;
    const int4* tq = (const int4*)(tgts + (size_t)b * HW);

    // prologue: stage tile 0 into buf0 + per-thread target prefetch
    stage_wave(pb, seg0, cls, wid, lane);
    int4 tA = tq[(size_t)seg0 * TILE + tid];
    int4 tB;

    float sloc = 0.f;
    int cloc = 0;

#pragma unroll 1
    for (int i = 0; i < TPB; i += 2) {
        // ---- even sub-iter: tile i from buf0 (targets tA) ----
        stage_wave(pb, seg0 + i + 1, cls + BUFF, wid, lane);
        tB = tq[(size_t)(seg0 + i + 1) * TILE + tid];
        wait_and_barrier(wid);            // tile i resident (all waves)
        tile_compute(cls, tA, tid, sloc, cloc);
        read_done_barrier();              // everyone done reading buf0

        // ---- odd sub-iter: tile i+1 from buf1 (targets tB) ----
        if (i + 2 < TPB) {
            stage_wave(pb, seg0 + i + 2, cls, wid, lane);
            tA = tq[(size_t)(seg0 + i + 2) * TILE + tid];
            wait_and_barrier(wid);
        } else {
            __builtin_amdgcn_sched_barrier(0);
            asm volatile("s_waitcnt vmcnt(0)" ::: "memory");
            __builtin_amdgcn_s_barrier();
            __builtin_amdgcn_sched_barrier(0);
        }
        tile_compute(cls + BUFF, tB, tid, sloc, cloc);
        read_done_barrier();              // everyone done reading buf1
    }

    // block reduce -> one atomic pair per block (vmcnt fully drained above)
    const float wsum = wave_reduce_f(sloc);
    const int wcnt = wave_reduce_i(cloc);
    if (lane == 0) { sbuf[wid] = wsum; cbuf[wid] = wcnt; }
    __syncthreads();
    if (tid == 0) {
        atomicAdd(&sums[b], sbuf[0] + sbuf[1] + sbuf[2] + sbuf[3]);
        atomicAdd(&counts[b], cbuf[0] + cbuf[1] + cbuf[2] + cbuf[3]);
    }
}

// ---------------- finalize (1 block; fallback never triggered) --------------
__device__ float pixel_loss(const float* __restrict__ preds,
                            const int* __restrict__ tgts, int b, int i) {
    const float* p = preds + (size_t)b * CC * HW + i;
    const int t = tgts[(size_t)b * HW + i];
    float m = -1e30f, tv = 0.f;
#pragma unroll
    for (int c = 0; c < CC; ++c) {
        float v = p[(size_t)c * HW];
        m = fmaxf(m, v);
        tv = (c == t) ? v : tv;
    }
    float s = 0.f;
#pragma unroll
    for (int c = 0; c < CC; ++c) s += __expf(p[(size_t)c * HW] - m);
    return m - tv + __logf(s);
}

__device__ int block_reduce_int(int v, int* buf) {
    v = wave_reduce_i(v);
    const int wid = threadIdx.x >> 6, lane = threadIdx.x & 63;
    __syncthreads();
    if (lane == 0) buf[wid] = v;
    __syncthreads();
    return buf[0] + buf[1] + buf[2] + buf[3];
}
__device__ float block_reduce_f(float v, float* buf) {
    v = wave_reduce_f(v);
    const int wid = threadIdx.x >> 6, lane = threadIdx.x & 63;
    __syncthreads();
    if (lane == 0) buf[wid] = v;
    __syncthreads();
    return buf[0] + buf[1] + buf[2] + buf[3];
}

__global__ __launch_bounds__(256) void ohem_finalize(
    const float* __restrict__ preds, const int* __restrict__ tgts,
    const float* __restrict__ sums, const int* __restrict__ counts,
    float* __restrict__ out) {
    __shared__ int ibuf[4];
    __shared__ float fbuf[4];

    float total = 0.f;
    for (int b = 0; b < BB; ++b) {
        const int cnt = counts[b];
        const float sm = sums[b];
        float mean;
        if (cnt >= MIN_KEPT) {
            mean = sm / (float)cnt;   // top-n_over == exactly losses > THRESH
        } else {
            // fallback: top-MIN_KEPT via value bisection
            float lo = 0.f, hi = 88.f;
            for (int it = 0; it < 40; ++it) {
                const float mid = 0.5f * (lo + hi);
                int c = 0;
                for (int i = threadIdx.x; i < HW; i += 256)
                    c += (pixel_loss(preds, tgts, b, i) > mid) ? 1 : 0;
                c = block_reduce_int(c, ibuf);
                if (c >= MIN_KEPT) lo = mid; else hi = mid;
                __syncthreads();
            }
            float ssum = 0.f;
            int sc = 0;
            for (int i = threadIdx.x; i < HW; i += 256) {
                const float l = pixel_loss(preds, tgts, b, i);
                if (l > lo) { ssum += l; ++sc; }
            }
            ssum = block_reduce_f(ssum, fbuf);
            sc = block_reduce_int(sc, ibuf);
            const float kept = ssum + (float)(MIN_KEPT - sc) * lo;
            mean = kept / (float)MIN_KEPT;
        }
        total += mean;
        __syncthreads();
    }
    if (threadIdx.x == 0) out[0] = total / (float)BB;
}

extern "C" void kernel_launch(void* const* d_in, const int* in_sizes, int n_in,
                              void* d_out, int out_size, void* d_ws, size_t ws_size,
                              hipStream_t stream) {
    const float* preds = (const float*)d_in[0];
    const int* tgts = (const int*)d_in[1];
    float* out = (float*)d_out;

    float* sums = (float*)d_ws;               // 8 floats @ 0
    int* counts = (int*)((char*)d_ws + 64);   // 8 ints   @ 64

    hipMemsetAsync(d_ws, 0, 128, stream);

    ohem_main<<<dim3(NPBLK), 256, 0, stream>>>(preds, tgts, sums, counts);
    ohem_finalize<<<1, 256, 0, stream>>>(preds, tgts, sums, counts, out);
}

// Round 7
// 427.871 us; speedup vs baseline: 1.0145x; 1.0145x over previous
//
#include <hip/hip_runtime.h>

// OHEM loss, MI355X. B=8, C=19, H=512, W=1024.
// v8 == v7 resubmitted: r6 container failure audited as infra (kernel is a
// plain HIP kernel: no LDS staging, no DMA, no inline-asm waits, no raw
// barriers, indices bounded; nothing that can hang hardware). Same experiment.
// v7 theory: kernel family pinned at ~2.1 TB/s across occupancy/depth/
// destination/run-length. Remaining hypothesis: ~5000 concurrent streams with
// 2^21-byte jumps transfer ~256B per DRAM bank-row visit -> ~2 TB/s cap.
// Fix: FEW, LONG streams. Class-outer online softmax: each thread owns 32
// pixels' state (m,s,tv) in registers; kernel loops classes OUTER; per
// class-step a block reads a 32KB CONTIGUOUS span of one plane (8 coalesced
// 1KB wave-loads); chip-wide ~512 sequential streams.
// Main path: n_over = count(loss>0.7) >> MIN_KEPT, so kept_sum ==
// sum(loss where loss>0.7); no sort. Fallback via bisection in finalize.

#define BB 8
#define CC 19
#define HW (512 * 1024)        // pixels per plane
#define THRESH 0.7f
#define MIN_KEPT 10000
#define PPB 8192               // pixels per block (32 KB contiguous per class)
#define BPB (HW / PPB)         // 64 blocks per batch
#define NBLK (BPB * BB)        // 512 blocks
#define CHUNK 8                // float4 chunks per thread (32 pixels/thread)

__device__ __forceinline__ float wave_reduce_f(float v) {
#pragma unroll
    for (int off = 32; off > 0; off >>= 1) v += __shfl_down(v, off, 64);
    return v;
}
__device__ __forceinline__ int wave_reduce_i(int v) {
#pragma unroll
    for (int off = 32; off > 0; off >>= 1) v += __shfl_down(v, off, 64);
    return v;
}

// ---------------- main: class-outer online-softmax loss pass ----------------
__global__ __launch_bounds__(256) void ohem_main(
    const float* __restrict__ preds, const int* __restrict__ tgts,
    float* __restrict__ sums, int* __restrict__ counts) {

    const int tid = threadIdx.x;
    const int b = blockIdx.x / BPB;        // batch
    const int seg = blockIdx.x % BPB;      // 8192-pixel segment within batch
    const int f40 = seg * (PPB / 4);       // first float4 index of segment

    const float* pb = preds + (size_t)b * CC * HW;   // batch's plane base

    // targets: 32 pixels/thread, packed 4x u8 per u32 (values 0..18)
    unsigned tp[CHUNK];
    {
        const int4* tq = (const int4*)(tgts + (size_t)b * HW);
#pragma unroll
        for (int j = 0; j < CHUNK; ++j) {
            const int4 t = tq[f40 + j * 256 + tid];
            tp[j] = (unsigned)t.x | ((unsigned)t.y << 8) |
                    ((unsigned)t.z << 16) | ((unsigned)t.w << 24);
        }
    }

    // online-softmax state for 32 pixels, all in registers
    float4 m[CHUNK], s[CHUNK], tv[CHUNK];

    // class 0 initializes state
    {
        const float4* pl = (const float4*)pb;   // plane 0
#pragma unroll
        for (int j = 0; j < CHUNK; ++j) {
            const float4 a = pl[f40 + j * 256 + tid];
            m[j] = a;
            tv[j] = a;                          // correct if t==0; else overwritten
            s[j] = make_float4(1.f, 1.f, 1.f, 1.f);
        }
    }

    // classes 1..18: per step the block reads 32 KB CONTIGUOUS from plane c
#pragma unroll 1
    for (int c = 1; c < CC; ++c) {
        const float4* pl = (const float4*)(pb + (size_t)c * HW);
        float4 a[CHUNK];
#pragma unroll
        for (int j = 0; j < CHUNK; ++j)         // issue all 8 loads first (MLP)
            a[j] = pl[f40 + j * 256 + tid];
#pragma unroll
        for (int j = 0; j < CHUNK; ++j) {
#define ONLINE(comp, sh)                                                      \
            {                                                                 \
                const float av = a[j].comp;                                   \
                const float nm = fmaxf(m[j].comp, av);                        \
                s[j].comp = s[j].comp * __expf(m[j].comp - nm) +              \
                            __expf(av - nm);                                  \
                m[j].comp = nm;                                               \
                const int tc = (int)((tp[j] >> (sh)) & 255u);                 \
                tv[j].comp = (tc == c) ? av : tv[j].comp;                     \
            }
            ONLINE(x, 0) ONLINE(y, 8) ONLINE(z, 16) ONLINE(w, 24)
#undef ONLINE
        }
    }

    // finish: per-pixel loss, threshold, accumulate
    float sloc = 0.f;
    int cloc = 0;
#pragma unroll
    for (int j = 0; j < CHUNK; ++j) {
        const float l0 = m[j].x - tv[j].x + __logf(s[j].x);
        const float l1 = m[j].y - tv[j].y + __logf(s[j].y);
        const float l2 = m[j].z - tv[j].z + __logf(s[j].z);
        const float l3 = m[j].w - tv[j].w + __logf(s[j].w);
        if (l0 > THRESH) { sloc += l0; ++cloc; }
        if (l1 > THRESH) { sloc += l1; ++cloc; }
        if (l2 > THRESH) { sloc += l2; ++cloc; }
        if (l3 > THRESH) { sloc += l3; ++cloc; }
    }

    // block reduce -> one atomic pair per block
    __shared__ float sbuf[4];
    __shared__ int cbuf[4];
    const float wsum = wave_reduce_f(sloc);
    const int wcnt = wave_reduce_i(cloc);
    const int wid = tid >> 6;
    const int lane = tid & 63;
    if (lane == 0) { sbuf[wid] = wsum; cbuf[wid] = wcnt; }
    __syncthreads();
    if (tid == 0) {
        atomicAdd(&sums[b], sbuf[0] + sbuf[1] + sbuf[2] + sbuf[3]);
        atomicAdd(&counts[b], cbuf[0] + cbuf[1] + cbuf[2] + cbuf[3]);
    }
}

// ---------------- finalize (1 block; fallback never triggered) --------------
__device__ float pixel_loss(const float* __restrict__ preds,
                            const int* __restrict__ tgts, int b, int i) {
    const float* p = preds + (size_t)b * CC * HW + i;
    const int t = tgts[(size_t)b * HW + i];
    float m = -1e30f, tv = 0.f;
#pragma unroll
    for (int c = 0; c < CC; ++c) {
        float v = p[(size_t)c * HW];
        m = fmaxf(m, v);
        tv = (c == t) ? v : tv;
    }
    float s = 0.f;
#pragma unroll
    for (int c = 0; c < CC; ++c) s += __expf(p[(size_t)c * HW] - m);
    return m - tv + __logf(s);
}

__device__ int block_reduce_int(int v, int* buf) {
    v = wave_reduce_i(v);
    const int wid = threadIdx.x >> 6, lane = threadIdx.x & 63;
    __syncthreads();
    if (lane == 0) buf[wid] = v;
    __syncthreads();
    return buf[0] + buf[1] + buf[2] + buf[3];
}
__device__ float block_reduce_f(float v, float* buf) {
    v = wave_reduce_f(v);
    const int wid = threadIdx.x >> 6, lane = threadIdx.x & 63;
    __syncthreads();
    if (lane == 0) buf[wid] = v;
    __syncthreads();
    return buf[0] + buf[1] + buf[2] + buf[3];
}

__global__ __launch_bounds__(256) void ohem_finalize(
    const float* __restrict__ preds, const int* __restrict__ tgts,
    const float* __restrict__ sums, const int* __restrict__ counts,
    float* __restrict__ out) {
    __shared__ int ibuf[4];
    __shared__ float fbuf[4];

    float total = 0.f;
    for (int b = 0; b < BB; ++b) {
        const int cnt = counts[b];
        const float sm = sums[b];
        float mean;
        if (cnt >= MIN_KEPT) {
            mean = sm / (float)cnt;   // top-n_over == exactly losses > THRESH
        } else {
            // fallback: top-MIN_KEPT via value bisection
            float lo = 0.f, hi = 88.f;
            for (int it = 0; it < 40; ++it) {
                const float mid = 0.5f * (lo + hi);
                int c = 0;
                for (int i = threadIdx.x; i < HW; i += 256)
                    c += (pixel_loss(preds, tgts, b, i) > mid) ? 1 : 0;
                c = block_reduce_int(c, ibuf);
                if (c >= MIN_KEPT) lo = mid; else hi = mid;
                __syncthreads();
            }
            float ssum = 0.f;
            int sc = 0;
            for (int i = threadIdx.x; i < HW; i += 256) {
                const float l = pixel_loss(preds, tgts, b, i);
                if (l > lo) { ssum += l; ++sc; }
            }
            ssum = block_reduce_f(ssum, fbuf);
            sc = block_reduce_int(sc, ibuf);
            const float kept = ssum + (float)(MIN_KEPT - sc) * lo;
            mean = kept / (float)MIN_KEPT;
        }
        total += mean;
        __syncthreads();
    }
    if (threadIdx.x == 0) out[0] = total / (float)BB;
}

extern "C" void kernel_launch(void* const* d_in, const int* in_sizes, int n_in,
                              void* d_out, int out_size, void* d_ws, size_t ws_size,
                              hipStream_t stream) {
    const float* preds = (const float*)d_in[0];
    const int* tgts = (const int*)d_in[1];
    float* out = (float*)d_out;

    float* sums = (float*)d_ws;               // 8 floats @ 0
    int* counts = (int*)((char*)d_ws + 64);   // 8 ints   @ 64

    hipMemsetAsync(d_ws, 0, 128, stream);

    ohem_main<<<dim3(NBLK), 256, 0, stream>>>(preds, tgts, sums, counts);
    ohem_finalize<<<1, 256, 0, stream>>>(preds, tgts, sums, counts, out);
}